// Round 4
// baseline (1494.966 us; speedup 1.0000x reference)
//
#include <hip/hip_runtime.h>

#define HH 32
#define LOG2E 1.44269504088896340736f
#define KCH 16   // TF pipeline chunk length (steps per ring half)
#define WPAD 36  // padded row stride (floats) for LDS-resident Whh1

typedef float v2f __attribute__((ext_vector_type(2)));

// DPP: quad_perm broadcasts (gate q = lane&3) and row rotates (16-lane rows)
#define DPPF(v, ctrl) \
    __int_as_float(__builtin_amdgcn_update_dpp(0, __float_as_int(v), (ctrl), 0xF, 0xF, true))
#define QP_B0 0x00   // [0,0,0,0] -> gate i to all quad lanes
#define QP_B1 0x55   // [1,1,1,1] -> gate f
#define QP_B2 0xAA   // [2,2,2,2] -> gate g
#define QP_B3 0xFF   // [3,3,3,3] -> gate o
#define DPP_ROR4  0x124
#define DPP_ROR8  0x128
#define SWZ(v, pat) __int_as_float(__builtin_amdgcn_ds_swizzle(__float_as_int(v), (pat)))

__device__ __forceinline__ float hw_exp2(float x) {
    float r; asm("v_exp_f32 %0, %1" : "=v"(r) : "v"(x)); return r;
}
__device__ __forceinline__ float sigm_e(float z, float e) {
    return __builtin_amdgcn_rcpf(1.0f + hw_exp2(z * e));
}
__device__ __forceinline__ v2f pk_fma(v2f a, v2f b, v2f c) {
    return __builtin_elementwise_fma(a, b, c);   // v_pk_fma_f32
}
__device__ __forceinline__ void load_bc(const float* p, v2f* d) {
#pragma unroll
    for (int r = 0; r < 8; ++r) {                // 8x ds_read_b128 broadcast
        float4 v = ((const float4*)p)[r];
        d[2*r]   = (v2f){v.x, v.y};
        d[2*r+1] = (v2f){v.z, v.w};
    }
}
// sum over 16 channel-groups: TF outputs only
__device__ __forceinline__ float out_reduce(float p) {
    p += DPPF(p, DPP_ROR4);
    p += DPPF(p, DPP_ROR8);
    p += SWZ(p, 0x401F);             // xor16
    p += __shfl_xor(p, 32, 64);
    return p;
}

// 2-row (A,B) dot over 16 v2f weight regs; ACC=false starts with pk_mul
template<bool ACC>
__device__ __forceinline__ void dot2(const v2f* hv, const v2f* mA, const v2f* mB,
                                     v2f& P0, v2f& P1, v2f& P2, v2f& P3) {
    if (ACC) {
        P0 = pk_fma(hv[0], mA[0], P0); P1 = pk_fma(hv[1], mA[1], P1);
        P2 = pk_fma(hv[0], mB[0], P2); P3 = pk_fma(hv[1], mB[1], P3);
    } else {
        P0 = hv[0] * mA[0]; P1 = hv[1] * mA[1];
        P2 = hv[0] * mB[0]; P3 = hv[1] * mB[1];
    }
#pragma unroll
    for (int r = 2; r < 16; r += 2) {
        P0 = pk_fma(hv[r],   mA[r],   P0);
        P1 = pk_fma(hv[r+1], mA[r+1], P1);
        P2 = pk_fma(hv[r],   mB[r],   P2);
        P3 = pk_fma(hv[r+1], mB[r+1], P3);
    }
}

__device__ __forceinline__ void gate_hc(float zA, float zB, float es, float mm, float cc,
                                        float& cA, float& cB, float& hA, float& hB) {
    float acA = fmaf(mm, sigm_e(zA, es), cc);
    float acB = fmaf(mm, sigm_e(zB, es), cc);
    float iA = DPPF(acA, QP_B0), fA = DPPF(acA, QP_B1);
    float gA = DPPF(acA, QP_B2), oA = DPPF(acA, QP_B3);
    float iB = DPPF(acB, QP_B0), fB = DPPF(acB, QP_B1);
    float gB = DPPF(acB, QP_B2), oB = DPPF(acB, QP_B3);
    cA = fmaf(fA, cA, iA * gA);
    cB = fmaf(fB, cB, iB * gB);
    hA = oA * fmaf(2.0f, sigm_e(cA, -2.0f * LOG2E), -1.0f);
    hB = oB * fmaf(2.0f, sigm_e(cB, -2.0f * LOG2E), -1.0f);
}

// Layout (both waves): q=lane&3 (gate 0=i 1=f 2=g 3=o), ch=lane>>2 (0..15).
// Lane owns rows rowA=(q<<5)|ch and rowB=(q<<5)|(ch+16).
// TF: 2-wave chunk pipeline (barrier per 16 steps). AR: SINGLE wave (w0),
// barrier-free; w1 hands off c2 and exits. Whh1 lives in padded LDS during AR
// (its dot is the off-critical-path shadow), Wih2/Whh2/Wlin in registers.
__global__ __launch_bounds__(128, 2)
void lstm_seq_kernel(const float* __restrict__ input,
                     const float* __restrict__ W_ih1, const float* __restrict__ W_hh1,
                     const float* __restrict__ b_ih1, const float* __restrict__ b_hh1,
                     const float* __restrict__ W_ih2, const float* __restrict__ W_hh2,
                     const float* __restrict__ b_ih2, const float* __restrict__ b_hh2,
                     const float* __restrict__ W_lin, const float* __restrict__ b_lin,
                     float* __restrict__ out, int T, int total)
{
    const int b    = blockIdx.x;     // one block (2 waves) per batch element
    const int tid  = threadIdx.x;
    const int w    = tid >> 6;       // wave0 = cell1 (+whole AR), wave1 = cell2 (+TF out)
    const int lane = tid & 63;
    const int q    = lane & 3;
    const int ch   = lane >> 2;      // 0..15
    const int rowA = (q << 5) | ch;
    const int rowB = (q << 5) | (ch + 16);

    __shared__ __align__(16) float ring[2 * KCH * HH];  // h1 stream (TF)
    __shared__ __align__(16) float h1x[HH];             // AR h1 self-roundtrip
    __shared__ __align__(16) float h2s[HH];             // h2 broadcast
    __shared__ __align__(16) float c2x[HH];             // c2 handoff w1 -> w0
    __shared__ __align__(16) float whh1l[128 * WPAD];   // Whh1, padded (AR shadow dot)

    const bool  isg = (q == 2);
    const float es  = isg ? (-2.0f * LOG2E) : (-LOG2E);
    const float mm  = isg ? 2.0f : 1.0f;
    const float cc  = isg ? -1.0f : 0.0f;

    // ---- per-wave weights ----
    // w0: m1=Whh1 rows, wl[16]=Wlin broadcast. w1: m1=Wih2 rows, m2=Whh2 rows.
    v2f m1A[16], m1B[16], m2A[16], m2B[16], wl[16];
    float wxA = 0.f, wxB = 0.f, bA, bB, wlA = 0.f, wlB = 0.f, blin;
    if (w == 0) {
        const v2f* pA = (const v2f*)(W_hh1 + rowA * HH);
        const v2f* pB = (const v2f*)(W_hh1 + rowB * HH);
        const v2f* wp = (const v2f*)W_lin;
#pragma unroll
        for (int r = 0; r < 16; ++r) { m1A[r] = pA[r]; m1B[r] = pB[r]; wl[r] = wp[r]; }
        wxA = W_ih1[rowA]; wxB = W_ih1[rowB];
        bA  = b_ih1[rowA] + b_hh1[rowA];
        bB  = b_ih1[rowB] + b_hh1[rowB];
    } else {
        const v2f* pA = (const v2f*)(W_ih2 + rowA * HH);
        const v2f* pB = (const v2f*)(W_ih2 + rowB * HH);
        const v2f* qA = (const v2f*)(W_hh2 + rowA * HH);
        const v2f* qB = (const v2f*)(W_hh2 + rowB * HH);
#pragma unroll
        for (int r = 0; r < 16; ++r) { m1A[r] = pA[r]; m1B[r] = pB[r];
                                       m2A[r] = qA[r]; m2B[r] = qB[r]; }
        bA  = b_ih2[rowA] + b_hh2[rowA];
        bB  = b_ih2[rowB] + b_hh2[rowB];
        wlA = W_lin[ch]; wlB = W_lin[ch + 16];
    }
    blin = b_lin[0];

    float cA = 0.f, cB = 0.f;        // c1 (wave0) / c2 (wave1)
    v2f p0 = {0.f,0.f}, p1 = {0.f,0.f}, p2 = {0.f,0.f}, p3 = {0.f,0.f};

    const float* __restrict__ inp  = input + (size_t)b * T;
    float* __restrict__       outp = out   + (size_t)b * total;

    // ================= Teacher-forced phase: chunk pipeline (unchanged) ==========
    if (w == 0) {
        int t = 0;
        float xcur = inp[0];
        for (int cb = 0; t < T; ++cb) {
            float* buf = ring + (cb & 1) * (KCH * HH);
            int S = T - t; if (S > KCH) S = KCH;
            for (int s = 0; s < S; ++s, ++t) {
                float x = xcur;
                int tn = t + 1;
                xcur = inp[tn < T ? tn : 0];            // prefetch, off-path
                float z1A = fmaf(x, wxA, bA + (p0.x + p0.y) + (p1.x + p1.y));
                float z1B = fmaf(x, wxB, bB + (p2.x + p2.y) + (p3.x + p3.y));
                float hA, hB;
                gate_hc(z1A, z1B, es, mm, cc, cA, cB, hA, hB);
                float* slot = buf + s * HH;
                if (q == 0) { slot[ch] = hA; slot[ch + 16] = hB; }
                v2f hv[16]; load_bc(slot, hv);           // same-wave round trip
                dot2<false>(hv, m1A, m1B, p0, p1, p2, p3);
            }
            __syncthreads();          // chunk published
        }
        __syncthreads();              // match consumer
    } else {
        __syncthreads();              // wait for chunk 0
        int t = 0;
        for (int cb = 0; t < T; ++cb) {
            const float* buf = ring + (cb & 1) * (KCH * HH);
            int S = T - t; if (S > KCH) S = KCH;
            for (int s = 0; s < S; ++s, ++t) {
                v2f hv[16]; load_bc(buf + s * HH, hv);
                dot2<true>(hv, m1A, m1B, p0, p1, p2, p3);   // in place: p dead after z2
                float z2A = bA + (p0.x + p0.y) + (p1.x + p1.y);
                float z2B = bB + (p2.x + p2.y) + (p3.x + p3.y);
                float hA, hB;
                gate_hc(z2A, z2B, es, mm, cc, cA, cB, hA, hB);
                if (q == 0) { h2s[ch] = hA; h2s[ch + 16] = hB; }
                v2f gv[16]; load_bc(h2s, gv);            // same-wave round trip
                dot2<false>(gv, m2A, m2B, p0, p1, p2, p3);
                float pr = fmaf(hA, wlA, hB * wlB);
                float ov = out_reduce(pr) + blin;
                if (lane == 0) outp[t] = ov;
            }
            if (t >= T && q == 0) { c2x[ch] = cA; c2x[ch + 16] = cB; }  // c2 handoff
            __syncthreads();
        }
        return;                        // w1 done: frees its SIMD issue slot
    }

    // ================= Autoregressive phase: single wave, zero barriers ==========
    // Entering: p0..p3 = Whh1·h1(T-1); cA,cB = c1(T-1); h2s = h2(T-1); c2x = c2(T-1).
    // Copy Whh1 from registers into padded LDS (off-path shadow-dot source).
#pragma unroll
    for (int k = 0; k < 16; ++k) {
        ((v2f*)(whh1l + rowA * WPAD))[k] = m1A[k];
        ((v2f*)(whh1l + rowB * WPAD))[k] = m1B[k];
    }
    float c2A = c2x[ch], c2B = c2x[ch + 16];      // broadcast reads (post-barrier)
    // On-path weights into registers (m1/m2 slots are dead now -> reused by RA).
    v2f i2A[16], i2B[16], w2A[16], w2B[16];
    {
        const v2f* a1 = (const v2f*)(W_ih2 + rowA * HH);
        const v2f* a2 = (const v2f*)(W_ih2 + rowB * HH);
        const v2f* a3 = (const v2f*)(W_hh2 + rowA * HH);
        const v2f* a4 = (const v2f*)(W_hh2 + rowB * HH);
#pragma unroll
        for (int r = 0; r < 16; ++r) { i2A[r] = a1[r]; i2B[r] = a2[r];
                                       w2A[r] = a3[r]; w2B[r] = a4[r]; }
    }
    const float b2A = b_ih2[rowA] + b_hh2[rowA];
    const float b2B = b_ih2[rowB] + b_hh2[rowB];

    for (int t = T; t < total; ++t) {
        // ---- read h2(t-1), feedback + Whh2 carry ----
        v2f gv[16]; load_bc(h2s, gv);
        v2f oa = gv[0] * wl[0], ob = gv[1] * wl[1];
#pragma unroll
        for (int r = 2; r < 16; r += 2) { oa = pk_fma(gv[r],   wl[r],   oa);
                                          ob = pk_fma(gv[r+1], wl[r+1], ob); }
        float xo = (oa.x + oa.y) + (ob.x + ob.y) + blin;   // = out(t-1)
        if (lane == 0) outp[t - 1] = xo;                   // off-path store
        v2f s0, s1, s2, s3;
        dot2<false>(gv, w2A, w2B, s0, s1, s2, s3);         // Whh2·h2(t-1)
        // ---- cell1 ----
        float z1A = fmaf(xo, wxA, bA + (p0.x + p0.y) + (p1.x + p1.y));
        float z1B = fmaf(xo, wxB, bB + (p2.x + p2.y) + (p3.x + p3.y));
        float hA, hB;
        gate_hc(z1A, z1B, es, mm, cc, cA, cB, hA, hB);     // c1 update
        if (q == 0) { h1x[ch] = hA; h1x[ch + 16] = hB; }
        v2f hv[16]; load_bc(h1x, hv);                      // same-wave round trip
        // ---- cell2 ----
        dot2<true>(hv, i2A, i2B, s0, s1, s2, s3);          // += Wih2·h1(t)
        float z2A = b2A + (s0.x + s0.y) + (s1.x + s1.y);
        float z2B = b2B + (s2.x + s2.y) + (s3.x + s3.y);
        float h2a, h2b;
        gate_hc(z2A, z2B, es, mm, cc, c2A, c2B, h2a, h2b); // c2 update
        if (q == 0) { h2s[ch] = h2a; h2s[ch + 16] = h2b; }
        // ---- shadow: Whh1·h1(t) from LDS (off-path, overlaps next h2 read) ----
        const float4* wrA = (const float4*)(whh1l + rowA * WPAD);
        const float4* wrB = (const float4*)(whh1l + rowB * WPAD);
        float4 wa = wrA[0], wb = wrB[0];
        p0 = (v2f){wa.x, wa.y} * hv[0]; p1 = (v2f){wa.z, wa.w} * hv[1];
        p2 = (v2f){wb.x, wb.y} * hv[0]; p3 = (v2f){wb.z, wb.w} * hv[1];
#pragma unroll
        for (int k = 1; k < 8; ++k) {
            float4 ua = wrA[k], ub = wrB[k];
            p0 = pk_fma((v2f){ua.x, ua.y}, hv[2*k],   p0);
            p1 = pk_fma((v2f){ua.z, ua.w}, hv[2*k+1], p1);
            p2 = pk_fma((v2f){ub.x, ub.y}, hv[2*k],   p2);
            p3 = pk_fma((v2f){ub.z, ub.w}, hv[2*k+1], p3);
        }
    }
    // tail: out(total-1) = Wlin·h2(total-1) + blin
    {
        v2f gv[16]; load_bc(h2s, gv);
        v2f oa = gv[0] * wl[0], ob = gv[1] * wl[1];
#pragma unroll
        for (int r = 2; r < 16; r += 2) { oa = pk_fma(gv[r],   wl[r],   oa);
                                          ob = pk_fma(gv[r+1], wl[r+1], ob); }
        if (lane == 0) outp[total - 1] = (oa.x + oa.y) + (ob.x + ob.y) + blin;
    }
}

extern "C" void kernel_launch(void* const* d_in, const int* in_sizes, int n_in,
                              void* d_out, int out_size, void* d_ws, size_t ws_size,
                              hipStream_t stream) {
    const int B = 1024;                 // fixed by the source module
    const int T = in_sizes[0] / B;      // 999
    const int total = out_size / B;     // T + future = 1999

    lstm_seq_kernel<<<dim3(B), dim3(128), 0, stream>>>(
        (const float*)d_in[0],
        (const float*)d_in[1], (const float*)d_in[2],
        (const float*)d_in[3], (const float*)d_in[4],
        (const float*)d_in[5], (const float*)d_in[6],
        (const float*)d_in[7], (const float*)d_in[8],
        (const float*)d_in[9], (const float*)d_in[10],
        (float*)d_out, T, total);
}

// Round 5
// 1420.021 us; speedup vs baseline: 1.0528x; 1.0528x over previous
//
#include <hip/hip_runtime.h>

#define HH 32
#define LOG2E 1.44269504088896340736f
#define KCH 16   // TF pipeline chunk length (steps per ring half)
#define WPAD 36  // padded row stride (floats) for LDS-resident Whh1 (16B aligned, bank-spread)

typedef float v2f __attribute__((ext_vector_type(2)));

// DPP: quad_perm broadcasts (gate q = lane&3) and row rotates (16-lane rows)
#define DPPF(v, ctrl) \
    __int_as_float(__builtin_amdgcn_update_dpp(0, __float_as_int(v), (ctrl), 0xF, 0xF, true))
#define QP_B0 0x00   // [0,0,0,0] -> gate i to all quad lanes
#define QP_B1 0x55   // [1,1,1,1] -> gate f
#define QP_B2 0xAA   // [2,2,2,2] -> gate g
#define QP_B3 0xFF   // [3,3,3,3] -> gate o
#define DPP_ROR4  0x124
#define DPP_ROR8  0x128
#define SWZ(v, pat) __int_as_float(__builtin_amdgcn_ds_swizzle(__float_as_int(v), (pat)))

__device__ __forceinline__ float hw_exp2(float x) {
    float r; asm("v_exp_f32 %0, %1" : "=v"(r) : "v"(x)); return r;
}
__device__ __forceinline__ float sigm_e(float z, float e) {
    return __builtin_amdgcn_rcpf(1.0f + hw_exp2(z * e));
}
__device__ __forceinline__ v2f pk_fma(v2f a, v2f b, v2f c) {
    return __builtin_elementwise_fma(a, b, c);   // v_pk_fma_f32
}
__device__ __forceinline__ void load_bc(const float* p, v2f* d) {
#pragma unroll
    for (int r = 0; r < 8; ++r) {                // 8x ds_read_b128 broadcast
        float4 v = ((const float4*)p)[r];
        d[2*r]   = (v2f){v.x, v.y};
        d[2*r+1] = (v2f){v.z, v.w};
    }
}
// TF output path: full cross-lane sum (uses LDS-pipe ops; off AR path)
__device__ __forceinline__ float out_reduce(float p) {
    p += DPPF(p, DPP_ROR4);
    p += DPPF(p, DPP_ROR8);
    p += SWZ(p, 0x401F);             // xor16
    p += __shfl_xor(p, 32, 64);
    return p;
}
__device__ __forceinline__ float rl(float v, int lane) {
    return __int_as_float(__builtin_amdgcn_readlane(__float_as_int(v), lane));
}
// AR feedback: pure VALU/SALU reduce (no LDS pipe). p quad-uniform per lane.
__device__ __forceinline__ float xo_reduce(float p) {
    p += DPPF(p, DPP_ROR4);          // + next quad's value
    p += DPPF(p, DPP_ROR8);          // each lane = its 16-lane row's sum (4 ch)
    float a0 = rl(p, 0), a1 = rl(p, 16), a2 = rl(p, 32), a3 = rl(p, 48);
    return (a0 + a1) + (a2 + a3);    // uniform across lanes
}

// 2-row (A,B) dot over 16 v2f weight regs; ACC=false starts with pk_mul
template<bool ACC>
__device__ __forceinline__ void dot2(const v2f* hv, const v2f* mA, const v2f* mB,
                                     v2f& P0, v2f& P1, v2f& P2, v2f& P3) {
    if (ACC) {
        P0 = pk_fma(hv[0], mA[0], P0); P1 = pk_fma(hv[1], mA[1], P1);
        P2 = pk_fma(hv[0], mB[0], P2); P3 = pk_fma(hv[1], mB[1], P3);
    } else {
        P0 = hv[0] * mA[0]; P1 = hv[1] * mA[1];
        P2 = hv[0] * mB[0]; P3 = hv[1] * mB[1];
    }
#pragma unroll
    for (int r = 2; r < 16; r += 2) {
        P0 = pk_fma(hv[r],   mA[r],   P0);
        P1 = pk_fma(hv[r+1], mA[r+1], P1);
        P2 = pk_fma(hv[r],   mB[r],   P2);
        P3 = pk_fma(hv[r+1], mB[r+1], P3);
    }
}

__device__ __forceinline__ void gate_hc(float zA, float zB, float es, float mm, float cc,
                                        float& cA, float& cB, float& hA, float& hB) {
    float acA = fmaf(mm, sigm_e(zA, es), cc);
    float acB = fmaf(mm, sigm_e(zB, es), cc);
    float iA = DPPF(acA, QP_B0), fA = DPPF(acA, QP_B1);
    float gA = DPPF(acA, QP_B2), oA = DPPF(acA, QP_B3);
    float iB = DPPF(acB, QP_B0), fB = DPPF(acB, QP_B1);
    float gB = DPPF(acB, QP_B2), oB = DPPF(acB, QP_B3);
    cA = fmaf(fA, cA, iA * gA);
    cB = fmaf(fB, cB, iB * gB);
    hA = oA * fmaf(2.0f, sigm_e(cA, -2.0f * LOG2E), -1.0f);
    hB = oB * fmaf(2.0f, sigm_e(cB, -2.0f * LOG2E), -1.0f);
}

// Layout (both waves): q=lane&3 (gate 0=i 1=f 2=g 3=o), ch=lane>>2 (0..15).
// Lane owns rows rowA=(q<<5)|ch and rowB=(q<<5)|(ch+16).
// TF: 2-wave chunk pipeline (verified 1205us structure). AR: SINGLE wave (w0),
// zero barriers; feedback xo via DPP+readlane (no LDS); Wih2/Whh2 in registers;
// Whh1 in padded LDS, reads issued mid-iteration so in-order returns never block.
__global__ __launch_bounds__(128, 2)
void lstm_seq_kernel(const float* __restrict__ input,
                     const float* __restrict__ W_ih1, const float* __restrict__ W_hh1,
                     const float* __restrict__ b_ih1, const float* __restrict__ b_hh1,
                     const float* __restrict__ W_ih2, const float* __restrict__ W_hh2,
                     const float* __restrict__ b_ih2, const float* __restrict__ b_hh2,
                     const float* __restrict__ W_lin, const float* __restrict__ b_lin,
                     float* __restrict__ out, int T, int total)
{
    const int b    = blockIdx.x;     // one block (2 waves) per batch element
    const int tid  = threadIdx.x;
    const int w    = tid >> 6;       // wave0 = cell1 (+whole AR), wave1 = cell2 (+TF out)
    const int lane = tid & 63;
    const int q    = lane & 3;
    const int ch   = lane >> 2;      // 0..15
    const int rowA = (q << 5) | ch;
    const int rowB = (q << 5) | (ch + 16);

    __shared__ __align__(16) float ring[2 * KCH * HH];  // h1 stream (TF)
    __shared__ __align__(16) float h1x[HH];             // AR h1 self-roundtrip
    __shared__ __align__(16) float h2s[HH];             // h2 broadcast
    __shared__ __align__(16) float c2x[HH];             // c2 handoff w1 -> w0
    __shared__ __align__(16) float whh1l[128 * WPAD];   // Whh1, padded (AR shadow dot)

    const bool  isg = (q == 2);
    const float es  = isg ? (-2.0f * LOG2E) : (-LOG2E);
    const float mm  = isg ? 2.0f : 1.0f;
    const float cc  = isg ? -1.0f : 0.0f;

    // ---- per-wave weights ----
    // w0: m1=Whh1 rows. w1: m1=Wih2 rows, m2=Whh2 rows.
    v2f m1A[16], m1B[16], m2A[16], m2B[16];
    float wxA = 0.f, wxB = 0.f, bA, bB, blin;
    const float wlA = W_lin[ch], wlB = W_lin[ch + 16];
    if (w == 0) {
        const v2f* pA = (const v2f*)(W_hh1 + rowA * HH);
        const v2f* pB = (const v2f*)(W_hh1 + rowB * HH);
#pragma unroll
        for (int r = 0; r < 16; ++r) { m1A[r] = pA[r]; m1B[r] = pB[r]; }
        wxA = W_ih1[rowA]; wxB = W_ih1[rowB];
        bA  = b_ih1[rowA] + b_hh1[rowA];
        bB  = b_ih1[rowB] + b_hh1[rowB];
    } else {
        const v2f* pA = (const v2f*)(W_ih2 + rowA * HH);
        const v2f* pB = (const v2f*)(W_ih2 + rowB * HH);
        const v2f* qA = (const v2f*)(W_hh2 + rowA * HH);
        const v2f* qB = (const v2f*)(W_hh2 + rowB * HH);
#pragma unroll
        for (int r = 0; r < 16; ++r) { m1A[r] = pA[r]; m1B[r] = pB[r];
                                       m2A[r] = qA[r]; m2B[r] = qB[r]; }
        bA  = b_ih2[rowA] + b_hh2[rowA];
        bB  = b_ih2[rowB] + b_hh2[rowB];
    }
    blin = b_lin[0];

    float cA = 0.f, cB = 0.f;        // c1 (wave0) / c2 (wave1)
    v2f p0 = {0.f,0.f}, p1 = {0.f,0.f}, p2 = {0.f,0.f}, p3 = {0.f,0.f};

    const float* __restrict__ inp  = input + (size_t)b * T;
    float* __restrict__       outp = out   + (size_t)b * total;

    // ================= Teacher-forced phase: chunk pipeline (unchanged) ==========
    if (w == 0) {
        int t = 0;
        float xcur = inp[0];
        for (int cb = 0; t < T; ++cb) {
            float* buf = ring + (cb & 1) * (KCH * HH);
            int S = T - t; if (S > KCH) S = KCH;
            for (int s = 0; s < S; ++s, ++t) {
                float x = xcur;
                int tn = t + 1;
                xcur = inp[tn < T ? tn : 0];            // prefetch, off-path
                float z1A = fmaf(x, wxA, bA + (p0.x + p0.y) + (p1.x + p1.y));
                float z1B = fmaf(x, wxB, bB + (p2.x + p2.y) + (p3.x + p3.y));
                float hA, hB;
                gate_hc(z1A, z1B, es, mm, cc, cA, cB, hA, hB);
                float* slot = buf + s * HH;
                if (q == 0) { slot[ch] = hA; slot[ch + 16] = hB; }
                v2f hv[16]; load_bc(slot, hv);           // same-wave round trip
                dot2<false>(hv, m1A, m1B, p0, p1, p2, p3);
            }
            __syncthreads();          // chunk published
        }
        __syncthreads();              // match consumer
    } else {
        __syncthreads();              // wait for chunk 0
        int t = 0;
        for (int cb = 0; t < T; ++cb) {
            const float* buf = ring + (cb & 1) * (KCH * HH);
            int S = T - t; if (S > KCH) S = KCH;
            for (int s = 0; s < S; ++s, ++t) {
                v2f hv[16]; load_bc(buf + s * HH, hv);
                dot2<true>(hv, m1A, m1B, p0, p1, p2, p3);   // in place: p dead after z2
                float z2A = bA + (p0.x + p0.y) + (p1.x + p1.y);
                float z2B = bB + (p2.x + p2.y) + (p3.x + p3.y);
                float hA, hB;
                gate_hc(z2A, z2B, es, mm, cc, cA, cB, hA, hB);
                if (q == 0) { h2s[ch] = hA; h2s[ch + 16] = hB; }
                v2f gv[16]; load_bc(h2s, gv);            // same-wave round trip
                dot2<false>(gv, m2A, m2B, p0, p1, p2, p3);
                float pr = fmaf(hA, wlA, hB * wlB);
                float ov = out_reduce(pr) + blin;
                if (lane == 0) outp[t] = ov;
            }
            if (t >= T && q == 0) { c2x[ch] = cA; c2x[ch + 16] = cB; }  // c2 handoff
            __syncthreads();
        }
        return;                        // w1 done
    }

    // ================= Autoregressive phase: single wave, zero barriers ==========
    // Entering: p0..p3 = Whh1·h1(T-1); cA,cB = c1(T-1); h2s = h2(T-1); c2x = c2(T-1).
    // Dump Whh1 registers into padded LDS (only the shadow dot reads it).
#pragma unroll
    for (int k = 0; k < 8; ++k) {
        ((float4*)(whh1l + rowA * WPAD))[k] =
            make_float4(m1A[2*k].x, m1A[2*k].y, m1A[2*k+1].x, m1A[2*k+1].y);
        ((float4*)(whh1l + rowB * WPAD))[k] =
            make_float4(m1B[2*k].x, m1B[2*k].y, m1B[2*k+1].x, m1B[2*k+1].y);
    }
    float h2a = h2s[ch], h2b = h2s[ch + 16];      // h2(T-1) per-lane registers
    float c2A = c2x[ch], c2B = c2x[ch + 16];
    // On-path cell2 weights into registers (m1/m2 slots dead -> reused by RA).
    v2f i2A[16], i2B[16], w2A[16], w2B[16];
    {
        const v2f* a1 = (const v2f*)(W_ih2 + rowA * HH);
        const v2f* a2 = (const v2f*)(W_ih2 + rowB * HH);
        const v2f* a3 = (const v2f*)(W_hh2 + rowA * HH);
        const v2f* a4 = (const v2f*)(W_hh2 + rowB * HH);
#pragma unroll
        for (int r = 0; r < 16; ++r) { i2A[r] = a1[r]; i2B[r] = a2[r];
                                       w2A[r] = a3[r]; w2B[r] = a4[r]; }
    }
    const float b2A = b_ih2[rowA] + b_hh2[rowA];
    const float b2B = b_ih2[rowB] + b_hh2[rowB];
    v2f gv[16]; load_bc(h2s, gv);                 // h2(T-1) vector for Whh2 dot

    for (int t = T; t < total; ++t) {
        // ---- feedback xo = Wlin·h2(t-1) + blin : pure VALU reduce ----
        float pr = fmaf(h2a, wlA, h2b * wlB);
        float xo = xo_reduce(pr) + blin;
        if (t > T && lane == 0) outp[t - 1] = xo;          // off-path store
        // ---- cell1 ----
        float z1A = fmaf(xo, wxA, bA + (p0.x + p0.y) + (p1.x + p1.y));
        float z1B = fmaf(xo, wxB, bB + (p2.x + p2.y) + (p3.x + p3.y));
        float hA, hB;
        gate_hc(z1A, z1B, es, mm, cc, cA, cB, hA, hB);     // c1 update
        if (q == 0) { h1x[ch] = hA; h1x[ch + 16] = hB; }
        v2f hv[16]; load_bc(h1x, hv);                      // broadcast roundtrip (8)
        // ---- issue Whh1 shadow reads NOW (16 per-lane b128, consumed at loop end);
        //      opaque zero blocks LICM from hoisting them into 64 registers ----
        int oz; asm volatile("v_mov_b32 %0, 0" : "=v"(oz));
        const float4* wrA = (const float4*)(whh1l + rowA * WPAD + oz);
        const float4* wrB = (const float4*)(whh1l + rowB * WPAD + oz);
        float4 wa0 = wrA[0], wa1 = wrA[1], wa2 = wrA[2], wa3 = wrA[3];
        float4 wa4 = wrA[4], wa5 = wrA[5], wa6 = wrA[6], wa7 = wrA[7];
        float4 wb0 = wrB[0], wb1 = wrB[1], wb2 = wrB[2], wb3 = wrB[3];
        float4 wb4 = wrB[4], wb5 = wrB[5], wb6 = wrB[6], wb7 = wrB[7];
        // ---- Whh2·h2(t-1) from gv (regs, loaded last iter) ----
        v2f s0, s1, s2, s3;
        dot2<false>(gv, w2A, w2B, s0, s1, s2, s3);
        // ---- += Wih2·h1(t) (waits hv only; wr still outstanding) ----
        dot2<true>(hv, i2A, i2B, s0, s1, s2, s3);
        float z2A = b2A + (s0.x + s0.y) + (s1.x + s1.y);
        float z2B = b2B + (s2.x + s2.y) + (s3.x + s3.y);
        float h2n, h2m;
        gate_hc(z2A, z2B, es, mm, cc, c2A, c2B, h2n, h2m); // c2 update
        h2a = h2n; h2b = h2m;
        if (q == 0) { h2s[ch] = h2a; h2s[ch + 16] = h2b; }
        // ---- shadow: Whh1·h1(t) (wr data has arrived under the dots/gate above) ----
        p0 = (v2f){wa0.x, wa0.y} * hv[0]; p1 = (v2f){wa0.z, wa0.w} * hv[1];
        p2 = (v2f){wb0.x, wb0.y} * hv[0]; p3 = (v2f){wb0.z, wb0.w} * hv[1];
        p0 = pk_fma((v2f){wa1.x, wa1.y}, hv[2],  p0); p1 = pk_fma((v2f){wa1.z, wa1.w}, hv[3],  p1);
        p2 = pk_fma((v2f){wb1.x, wb1.y}, hv[2],  p2); p3 = pk_fma((v2f){wb1.z, wb1.w}, hv[3],  p3);
        p0 = pk_fma((v2f){wa2.x, wa2.y}, hv[4],  p0); p1 = pk_fma((v2f){wa2.z, wa2.w}, hv[5],  p1);
        p2 = pk_fma((v2f){wb2.x, wb2.y}, hv[4],  p2); p3 = pk_fma((v2f){wb2.z, wb2.w}, hv[5],  p3);
        p0 = pk_fma((v2f){wa3.x, wa3.y}, hv[6],  p0); p1 = pk_fma((v2f){wa3.z, wa3.w}, hv[7],  p1);
        p2 = pk_fma((v2f){wb3.x, wb3.y}, hv[6],  p2); p3 = pk_fma((v2f){wb3.z, wb3.w}, hv[7],  p3);
        p0 = pk_fma((v2f){wa4.x, wa4.y}, hv[8],  p0); p1 = pk_fma((v2f){wa4.z, wa4.w}, hv[9],  p1);
        p2 = pk_fma((v2f){wb4.x, wb4.y}, hv[8],  p2); p3 = pk_fma((v2f){wb4.z, wb4.w}, hv[9],  p3);
        p0 = pk_fma((v2f){wa5.x, wa5.y}, hv[10], p0); p1 = pk_fma((v2f){wa5.z, wa5.w}, hv[11], p1);
        p2 = pk_fma((v2f){wb5.x, wb5.y}, hv[10], p2); p3 = pk_fma((v2f){wb5.z, wb5.w}, hv[11], p3);
        p0 = pk_fma((v2f){wa6.x, wa6.y}, hv[12], p0); p1 = pk_fma((v2f){wa6.z, wa6.w}, hv[13], p1);
        p2 = pk_fma((v2f){wb6.x, wb6.y}, hv[12], p2); p3 = pk_fma((v2f){wb6.z, wb6.w}, hv[13], p3);
        p0 = pk_fma((v2f){wa7.x, wa7.y}, hv[14], p0); p1 = pk_fma((v2f){wa7.z, wa7.w}, hv[15], p1);
        p2 = pk_fma((v2f){wb7.x, wb7.y}, hv[14], p2); p3 = pk_fma((v2f){wb7.z, wb7.w}, hv[15], p3);
        // ---- reload gv = h2(t) LAST (broadcast; latency covered by next reduce+gate1) ----
        load_bc(h2s, gv);
    }
    // tail: out(total-1) = Wlin·h2(total-1) + blin (register-only reduce)
    {
        float pr = fmaf(h2a, wlA, h2b * wlB);
        float ov = xo_reduce(pr) + blin;
        if (lane == 0) outp[total - 1] = ov;
    }
}

extern "C" void kernel_launch(void* const* d_in, const int* in_sizes, int n_in,
                              void* d_out, int out_size, void* d_ws, size_t ws_size,
                              hipStream_t stream) {
    const int B = 1024;                 // fixed by the source module
    const int T = in_sizes[0] / B;      // 999
    const int total = out_size / B;     // T + future = 1999

    lstm_seq_kernel<<<dim3(B), dim3(128), 0, stream>>>(
        (const float*)d_in[0],
        (const float*)d_in[1], (const float*)d_in[2],
        (const float*)d_in[3], (const float*)d_in[4],
        (const float*)d_in[5], (const float*)d_in[6],
        (const float*)d_in[7], (const float*)d_in[8],
        (const float*)d_in[9], (const float*)d_in[10],
        (float*)d_out, T, total);
}

// Round 6
// 1236.364 us; speedup vs baseline: 1.2092x; 1.1485x over previous
//
#include <hip/hip_runtime.h>

#define HH 32
#define LOG2E 1.44269504088896340736f
#define KCH 16   // TF pipeline chunk length (steps per ring half)

typedef float v2f __attribute__((ext_vector_type(2)));

// DPP: quad_perm broadcasts (gate q = lane&3) and row rotates (16-lane rows)
#define DPPF(v, ctrl) \
    __int_as_float(__builtin_amdgcn_update_dpp(0, __float_as_int(v), (ctrl), 0xF, 0xF, true))
#define QP_B0 0x00   // [0,0,0,0] -> gate i to all quad lanes
#define QP_B1 0x55   // [1,1,1,1] -> gate f
#define QP_B2 0xAA   // [2,2,2,2] -> gate g
#define QP_B3 0xFF   // [3,3,3,3] -> gate o
#define DPP_ROR4  0x124
#define DPP_ROR8  0x128
#define SWZ(v, pat) __int_as_float(__builtin_amdgcn_ds_swizzle(__float_as_int(v), (pat)))

__device__ __forceinline__ float hw_exp2(float x) {
    float r; asm("v_exp_f32 %0, %1" : "=v"(r) : "v"(x)); return r;
}
__device__ __forceinline__ float sigm_e(float z, float e) {
    return __builtin_amdgcn_rcpf(1.0f + hw_exp2(z * e));
}
__device__ __forceinline__ v2f pk_fma(v2f a, v2f b, v2f c) {
    return __builtin_elementwise_fma(a, b, c);   // v_pk_fma_f32
}
__device__ __forceinline__ void load_bc(const float* p, v2f* d) {
#pragma unroll
    for (int r = 0; r < 8; ++r) {                // 8x ds_read_b128 broadcast (conflict-free)
        float4 v = ((const float4*)p)[r];
        d[2*r]   = (v2f){v.x, v.y};
        d[2*r+1] = (v2f){v.z, v.w};
    }
}
// TF output path: full cross-lane sum (off AR path)
__device__ __forceinline__ float out_reduce(float p) {
    p += DPPF(p, DPP_ROR4);
    p += DPPF(p, DPP_ROR8);
    p += SWZ(p, 0x401F);             // xor16
    p += __shfl_xor(p, 32, 64);
    return p;
}
__device__ __forceinline__ float rl(float v, int lane) {
    return __int_as_float(__builtin_amdgcn_readlane(__float_as_int(v), lane));
}
// AR feedback: pure VALU/SALU reduce (no LDS pipe). p quad-uniform per lane.
__device__ __forceinline__ float xo_reduce(float p) {
    p += DPPF(p, DPP_ROR4);          // + ch+1 within row
    p += DPPF(p, DPP_ROR8);          // each lane = its 16-lane row's 4-ch sum
    float a0 = rl(p, 0), a1 = rl(p, 16), a2 = rl(p, 32), a3 = rl(p, 48);
    return (a0 + a1) + (a2 + a3);    // uniform across lanes
}

// 2-row (A,B) dot over 16 v2f weight regs; ACC=false starts with pk_mul
template<bool ACC>
__device__ __forceinline__ void dot2(const v2f* hv, const v2f* mA, const v2f* mB,
                                     v2f& P0, v2f& P1, v2f& P2, v2f& P3) {
    if (ACC) {
        P0 = pk_fma(hv[0], mA[0], P0); P1 = pk_fma(hv[1], mA[1], P1);
        P2 = pk_fma(hv[0], mB[0], P2); P3 = pk_fma(hv[1], mB[1], P3);
    } else {
        P0 = hv[0] * mA[0]; P1 = hv[1] * mA[1];
        P2 = hv[0] * mB[0]; P3 = hv[1] * mB[1];
    }
#pragma unroll
    for (int r = 2; r < 16; r += 2) {
        P0 = pk_fma(hv[r],   mA[r],   P0);
        P1 = pk_fma(hv[r+1], mA[r+1], P1);
        P2 = pk_fma(hv[r],   mB[r],   P2);
        P3 = pk_fma(hv[r+1], mB[r+1], P3);
    }
}

__device__ __forceinline__ void gate_hc(float zA, float zB, float es, float mm, float cc,
                                        float& cA, float& cB, float& hA, float& hB) {
    float acA = fmaf(mm, sigm_e(zA, es), cc);
    float acB = fmaf(mm, sigm_e(zB, es), cc);
    float iA = DPPF(acA, QP_B0), fA = DPPF(acA, QP_B1);
    float gA = DPPF(acA, QP_B2), oA = DPPF(acA, QP_B3);
    float iB = DPPF(acB, QP_B0), fB = DPPF(acB, QP_B1);
    float gB = DPPF(acB, QP_B2), oB = DPPF(acB, QP_B3);
    cA = fmaf(fA, cA, iA * gA);
    cB = fmaf(fB, cB, iB * gB);
    hA = oA * fmaf(2.0f, sigm_e(cA, -2.0f * LOG2E), -1.0f);
    hB = oB * fmaf(2.0f, sigm_e(cB, -2.0f * LOG2E), -1.0f);
}

// Layout (both waves): q=lane&3 (gate 0=i 1=f 2=g 3=o), ch=lane>>2 (0..15).
// Lane owns rows rowA=(q<<5)|ch and rowB=(q<<5)|(ch+16).
// TF: 2-wave chunk pipeline (verified 1205us structure). AR: SINGLE wave (w0),
// zero barriers, ALL THREE matrices (Whh1, Wih2, Whh2) register-resident;
// LDS used only for two conflict-free broadcast roundtrips per step.
__global__ __launch_bounds__(128, 2)
void lstm_seq_kernel(const float* __restrict__ input,
                     const float* __restrict__ W_ih1, const float* __restrict__ W_hh1,
                     const float* __restrict__ b_ih1, const float* __restrict__ b_hh1,
                     const float* __restrict__ W_ih2, const float* __restrict__ W_hh2,
                     const float* __restrict__ b_ih2, const float* __restrict__ b_hh2,
                     const float* __restrict__ W_lin, const float* __restrict__ b_lin,
                     float* __restrict__ out, int T, int total)
{
    const int b    = blockIdx.x;     // one block (2 waves) per batch element
    const int tid  = threadIdx.x;
    const int w    = tid >> 6;       // wave0 = cell1 (+whole AR), wave1 = cell2 (+TF out)
    const int lane = tid & 63;
    const int q    = lane & 3;
    const int ch   = lane >> 2;      // 0..15
    const int rowA = (q << 5) | ch;
    const int rowB = (q << 5) | (ch + 16);

    __shared__ __align__(16) float ring[2 * KCH * HH];  // h1 stream (TF)
    __shared__ __align__(16) float h1x[HH];             // AR h1 self-roundtrip
    __shared__ __align__(16) float h2s[HH];             // h2 broadcast
    __shared__ __align__(16) float c2x[HH];             // c2 handoff w1 -> w0

    const bool  isg = (q == 2);
    const float es  = isg ? (-2.0f * LOG2E) : (-LOG2E);
    const float mm  = isg ? 2.0f : 1.0f;
    const float cc  = isg ? -1.0f : 0.0f;

    // ---- per-wave weights ----
    // w0: m1=Whh1 rows. w1: m1=Wih2 rows, m2=Whh2 rows.
    v2f m1A[16], m1B[16], m2A[16], m2B[16];
    float wxA = 0.f, wxB = 0.f, bA, bB, blin;
    const float wlA = W_lin[ch], wlB = W_lin[ch + 16];
    if (w == 0) {
        const v2f* pA = (const v2f*)(W_hh1 + rowA * HH);
        const v2f* pB = (const v2f*)(W_hh1 + rowB * HH);
#pragma unroll
        for (int r = 0; r < 16; ++r) { m1A[r] = pA[r]; m1B[r] = pB[r]; }
        wxA = W_ih1[rowA]; wxB = W_ih1[rowB];
        bA  = b_ih1[rowA] + b_hh1[rowA];
        bB  = b_ih1[rowB] + b_hh1[rowB];
    } else {
        const v2f* pA = (const v2f*)(W_ih2 + rowA * HH);
        const v2f* pB = (const v2f*)(W_ih2 + rowB * HH);
        const v2f* qA = (const v2f*)(W_hh2 + rowA * HH);
        const v2f* qB = (const v2f*)(W_hh2 + rowB * HH);
#pragma unroll
        for (int r = 0; r < 16; ++r) { m1A[r] = pA[r]; m1B[r] = pB[r];
                                       m2A[r] = qA[r]; m2B[r] = qB[r]; }
        bA  = b_ih2[rowA] + b_hh2[rowA];
        bB  = b_ih2[rowB] + b_hh2[rowB];
    }
    blin = b_lin[0];

    float cA = 0.f, cB = 0.f;        // c1 (wave0) / c2 (wave1)
    v2f p0 = {0.f,0.f}, p1 = {0.f,0.f}, p2 = {0.f,0.f}, p3 = {0.f,0.f};

    const float* __restrict__ inp  = input + (size_t)b * T;
    float* __restrict__       outp = out   + (size_t)b * total;

    // ================= Teacher-forced phase: chunk pipeline (unchanged) ==========
    if (w == 0) {
        int t = 0;
        float xcur = inp[0];
        for (int cb = 0; t < T; ++cb) {
            float* buf = ring + (cb & 1) * (KCH * HH);
            int S = T - t; if (S > KCH) S = KCH;
            for (int s = 0; s < S; ++s, ++t) {
                float x = xcur;
                int tn = t + 1;
                xcur = inp[tn < T ? tn : 0];            // prefetch, off-path
                float z1A = fmaf(x, wxA, bA + (p0.x + p0.y) + (p1.x + p1.y));
                float z1B = fmaf(x, wxB, bB + (p2.x + p2.y) + (p3.x + p3.y));
                float hA, hB;
                gate_hc(z1A, z1B, es, mm, cc, cA, cB, hA, hB);
                float* slot = buf + s * HH;
                if (q == 0) { slot[ch] = hA; slot[ch + 16] = hB; }
                v2f hv[16]; load_bc(slot, hv);           // same-wave round trip
                dot2<false>(hv, m1A, m1B, p0, p1, p2, p3);
            }
            __syncthreads();          // chunk published
        }
        __syncthreads();              // match consumer
    } else {
        __syncthreads();              // wait for chunk 0
        int t = 0;
        for (int cb = 0; t < T; ++cb) {
            const float* buf = ring + (cb & 1) * (KCH * HH);
            int S = T - t; if (S > KCH) S = KCH;
            for (int s = 0; s < S; ++s, ++t) {
                v2f hv[16]; load_bc(buf + s * HH, hv);
                dot2<true>(hv, m1A, m1B, p0, p1, p2, p3);   // in place: p dead after z2
                float z2A = bA + (p0.x + p0.y) + (p1.x + p1.y);
                float z2B = bB + (p2.x + p2.y) + (p3.x + p3.y);
                float hA, hB;
                gate_hc(z2A, z2B, es, mm, cc, cA, cB, hA, hB);
                if (q == 0) { h2s[ch] = hA; h2s[ch + 16] = hB; }
                v2f gv[16]; load_bc(h2s, gv);            // same-wave round trip
                dot2<false>(gv, m2A, m2B, p0, p1, p2, p3);
                float pr = fmaf(hA, wlA, hB * wlB);
                float ov = out_reduce(pr) + blin;
                if (lane == 0) outp[t] = ov;
            }
            if (t >= T && q == 0) { c2x[ch] = cA; c2x[ch + 16] = cB; }  // c2 handoff
            __syncthreads();
        }
        return;                        // w1 done
    }

    // ================= Autoregressive phase: single wave, zero barriers ==========
    // Entering: p0..p3 = Whh1·h1(T-1); cA,cB = c1(T-1); h2s = h2(T-1); c2x = c2(T-1).
    // m1A/m1B (Whh1) stay in registers. Load cell2 weights into registers too.
    float h2a = h2s[ch], h2b = h2s[ch + 16];      // h2(T-1) per-lane registers
    float c2A = c2x[ch], c2B = c2x[ch + 16];
    v2f i2A[16], i2B[16], w2A[16], w2B[16];
    {
        const v2f* a1 = (const v2f*)(W_ih2 + rowA * HH);
        const v2f* a2 = (const v2f*)(W_ih2 + rowB * HH);
        const v2f* a3 = (const v2f*)(W_hh2 + rowA * HH);
        const v2f* a4 = (const v2f*)(W_hh2 + rowB * HH);
#pragma unroll
        for (int r = 0; r < 16; ++r) { i2A[r] = a1[r]; i2B[r] = a2[r];
                                       w2A[r] = a3[r]; w2B[r] = a4[r]; }
    }
    const float b2A = b_ih2[rowA] + b_hh2[rowA];
    const float b2B = b_ih2[rowB] + b_hh2[rowB];

    // tv: shared transient vector — holds gv (h2 broadcast) across the back-edge,
    // then hv (h1 broadcast) within the iteration; live ranges disjoint.
    v2f tv[16]; load_bc(h2s, tv);                 // gv = h2(T-1)

    for (int t = T; t < total; ++t) {
        // ---- feedback xo = Wlin·h2(t-1) + blin : register-only reduce ----
        float pr = fmaf(h2a, wlA, h2b * wlB);
        float xo = xo_reduce(pr) + blin;
        if (t > T && lane == 0) outp[t - 1] = xo;          // off-path store
        // ---- cell1 ----
        float z1A = fmaf(xo, wxA, bA + (p0.x + p0.y) + (p1.x + p1.y));
        float z1B = fmaf(xo, wxB, bB + (p2.x + p2.y) + (p3.x + p3.y));
        float hA, hB;
        gate_hc(z1A, z1B, es, mm, cc, cA, cB, hA, hB);     // c1 update
        // ---- Whh2·h2(t-1) from tv (independent of gate1; compiler interleaves) ----
        v2f s0, s1, s2, s3;
        dot2<false>(tv, w2A, w2B, s0, s1, s2, s3);         // tv(gv) dead after this
        // ---- h1 broadcast roundtrip ----
        if (q == 0) { h1x[ch] = hA; h1x[ch + 16] = hB; }
        load_bc(h1x, tv);                                  // tv = hv (8 b128, bcast)
        // ---- cell2: z2 = b2 + Whh2·h2 + Wih2·h1 ----
        dot2<true>(tv, i2A, i2B, s0, s1, s2, s3);
        float z2A = b2A + (s0.x + s0.y) + (s1.x + s1.y);
        float z2B = b2B + (s2.x + s2.y) + (s3.x + s3.y);
        float h2n, h2m;
        gate_hc(z2A, z2B, es, mm, cc, c2A, c2B, h2n, h2m); // c2 update
        h2a = h2n; h2b = h2m;
        // ---- shadow Whh1·h1(t): register-only (no LDS!) ----
        dot2<false>(tv, m1A, m1B, p0, p1, p2, p3);         // tv(hv) dead after this
        // ---- publish h2(t), prefetch gv for next iter (latency hidden by
        //      next iteration's xo_reduce + gate1) ----
        if (q == 0) { h2s[ch] = h2a; h2s[ch + 16] = h2b; }
        load_bc(h2s, tv);                                  // tv = gv
    }
    // tail: out(total-1) = Wlin·h2(total-1) + blin (register-only reduce)
    {
        float pr = fmaf(h2a, wlA, h2b * wlB);
        float ov = xo_reduce(pr) + blin;
        if (lane == 0) outp[total - 1] = ov;
    }
}

extern "C" void kernel_launch(void* const* d_in, const int* in_sizes, int n_in,
                              void* d_out, int out_size, void* d_ws, size_t ws_size,
                              hipStream_t stream) {
    const int B = 1024;                 // fixed by the source module
    const int T = in_sizes[0] / B;      // 999
    const int total = out_size / B;     // T + future = 1999

    lstm_seq_kernel<<<dim3(B), dim3(128), 0, stream>>>(
        (const float*)d_in[0],
        (const float*)d_in[1], (const float*)d_in[2],
        (const float*)d_in[3], (const float*)d_in[4],
        (const float*)d_in[5], (const float*)d_in[6],
        (const float*)d_in[7], (const float*)d_in[8],
        (const float*)d_in[9], (const float*)d_in[10],
        (float*)d_out, T, total);
}

// Round 7
// 1156.007 us; speedup vs baseline: 1.2932x; 1.0695x over previous
//
#include <hip/hip_runtime.h>

#define HH 32
#define LOG2E 1.44269504088896340736f
#define KCH 16   // TF pipeline chunk length (steps per ring half)

typedef float v2f __attribute__((ext_vector_type(2)));

// DPP: quad_perm broadcasts (gate q = lane&3) and row rotates (16-lane rows)
#define DPPF(v, ctrl) \
    __int_as_float(__builtin_amdgcn_update_dpp(0, __float_as_int(v), (ctrl), 0xF, 0xF, true))
#define QP_B0 0x00   // [0,0,0,0] -> gate i to all quad lanes
#define QP_B1 0x55   // [1,1,1,1] -> gate f
#define QP_B2 0xAA   // [2,2,2,2] -> gate g
#define QP_B3 0xFF   // [3,3,3,3] -> gate o
#define DPP_ROR4  0x124
#define DPP_ROR8  0x128
#define SWZ(v, pat) __int_as_float(__builtin_amdgcn_ds_swizzle(__float_as_int(v), (pat)))

__device__ __forceinline__ float hw_exp2(float x) {
    float r; asm("v_exp_f32 %0, %1" : "=v"(r) : "v"(x)); return r;
}
__device__ __forceinline__ float sigm_e(float z, float e) {
    return __builtin_amdgcn_rcpf(1.0f + hw_exp2(z * e));
}
__device__ __forceinline__ v2f pk_fma(v2f a, v2f b, v2f c) {
    return __builtin_elementwise_fma(a, b, c);   // v_pk_fma_f32
}
__device__ __forceinline__ void load_bc(const float* p, v2f* d) {
#pragma unroll
    for (int r = 0; r < 8; ++r) {                // 8x ds_read_b128 broadcast (conflict-free)
        float4 v = ((const float4*)p)[r];
        d[2*r]   = (v2f){v.x, v.y};
        d[2*r+1] = (v2f){v.z, v.w};
    }
}
// TF output path: full cross-lane sum
__device__ __forceinline__ float out_reduce(float p) {
    p += DPPF(p, DPP_ROR4);
    p += DPPF(p, DPP_ROR8);
    p += SWZ(p, 0x401F);             // xor16
    p += __shfl_xor(p, 32, 64);
    return p;
}

// 2-row (A,B) dot over 16 v2f weight regs; ACC=false starts with pk_mul
template<bool ACC>
__device__ __forceinline__ void dot2(const v2f* hv, const v2f* mA, const v2f* mB,
                                     v2f& P0, v2f& P1, v2f& P2, v2f& P3) {
    if (ACC) {
        P0 = pk_fma(hv[0], mA[0], P0); P1 = pk_fma(hv[1], mA[1], P1);
        P2 = pk_fma(hv[0], mB[0], P2); P3 = pk_fma(hv[1], mB[1], P3);
    } else {
        P0 = hv[0] * mA[0]; P1 = hv[1] * mA[1];
        P2 = hv[0] * mB[0]; P3 = hv[1] * mB[1];
    }
#pragma unroll
    for (int r = 2; r < 16; r += 2) {
        P0 = pk_fma(hv[r],   mA[r],   P0);
        P1 = pk_fma(hv[r+1], mA[r+1], P1);
        P2 = pk_fma(hv[r],   mB[r],   P2);
        P3 = pk_fma(hv[r+1], mB[r+1], P3);
    }
}

__device__ __forceinline__ void gate_hc(float zA, float zB, float es, float mm, float cc,
                                        float& cA, float& cB, float& hA, float& hB) {
    float acA = fmaf(mm, sigm_e(zA, es), cc);
    float acB = fmaf(mm, sigm_e(zB, es), cc);
    float iA = DPPF(acA, QP_B0), fA = DPPF(acA, QP_B1);
    float gA = DPPF(acA, QP_B2), oA = DPPF(acA, QP_B3);
    float iB = DPPF(acB, QP_B0), fB = DPPF(acB, QP_B1);
    float gB = DPPF(acB, QP_B2), oB = DPPF(acB, QP_B3);
    cA = fmaf(fA, cA, iA * gA);
    cB = fmaf(fB, cB, iB * gB);
    hA = oA * fmaf(2.0f, sigm_e(cA, -2.0f * LOG2E), -1.0f);
    hB = oB * fmaf(2.0f, sigm_e(cB, -2.0f * LOG2E), -1.0f);
}

// Layout (both waves): q=lane&3 (gate 0=i 1=f 2=g 3=o), ch=lane>>2 (0..15).
// Lane owns rows rowA=(q<<5)|ch and rowB=(q<<5)|(ch+16).
// TF REBALANCED: w0 = cell1 + Wih2·h1 partial dot (pre-reduced into zring);
//                w1 = cell2 gate + Whh2 dot + output (no h1 read, no ih2 dot).
// AR: r2-verified 2-wave structure (2 barriers/step, per-lane wl feedback on w0).
__global__ __launch_bounds__(128, 2)
void lstm_seq_kernel(const float* __restrict__ input,
                     const float* __restrict__ W_ih1, const float* __restrict__ W_hh1,
                     const float* __restrict__ b_ih1, const float* __restrict__ b_hh1,
                     const float* __restrict__ W_ih2, const float* __restrict__ W_hh2,
                     const float* __restrict__ b_ih2, const float* __restrict__ b_hh2,
                     const float* __restrict__ W_lin, const float* __restrict__ b_lin,
                     float* __restrict__ out, int T, int total)
{
    const int b    = blockIdx.x;     // one block (2 waves) per batch element
    const int tid  = threadIdx.x;
    const int w    = tid >> 6;       // wave0 = cell1 (+ih2 dot), wave1 = cell2 (+TF out)
    const int lane = tid & 63;
    const int q    = lane & 3;
    const int ch   = lane >> 2;      // 0..15
    const int rowA = (q << 5) | ch;
    const int rowB = (q << 5) | (ch + 16);
    const int zidx = (q << 4) | ch;  // 0..63; zidx%32 hits each bank with 2 lanes -> free

    __shared__ __align__(16) float zring[2 * KCH * 128]; // Wih2·h1(t) row partials
    __shared__ __align__(16) float h1self[HH];           // w0 TF self-roundtrip
    __shared__ __align__(16) float h1x[HH];              // AR h1 exchange
    __shared__ __align__(16) float h2s[HH];              // w1 h2 self-roundtrip / AR feedback

    const bool  isg = (q == 2);
    const float es  = isg ? (-2.0f * LOG2E) : (-LOG2E);
    const float mm  = isg ? 2.0f : 1.0f;
    const float cc  = isg ? -1.0f : 0.0f;

    // ---- per-wave weights ----
    // w0: m1=Whh1 rows, m2=Wih2 rows (TF partial dot). w1: m1=Wih2 rows, m2=Whh2 rows.
    v2f m1A[16], m1B[16], m2A[16], m2B[16];
    float wxA = 0.f, wxB = 0.f, bA, bB, blin;
    const float wlA = W_lin[ch], wlB = W_lin[ch + 16];
    if (w == 0) {
        const v2f* pA = (const v2f*)(W_hh1 + rowA * HH);
        const v2f* pB = (const v2f*)(W_hh1 + rowB * HH);
        const v2f* qA = (const v2f*)(W_ih2 + rowA * HH);
        const v2f* qB = (const v2f*)(W_ih2 + rowB * HH);
#pragma unroll
        for (int r = 0; r < 16; ++r) { m1A[r] = pA[r]; m1B[r] = pB[r];
                                       m2A[r] = qA[r]; m2B[r] = qB[r]; }
        wxA = W_ih1[rowA]; wxB = W_ih1[rowB];
        bA  = b_ih1[rowA] + b_hh1[rowA];
        bB  = b_ih1[rowB] + b_hh1[rowB];
    } else {
        const v2f* pA = (const v2f*)(W_ih2 + rowA * HH);
        const v2f* pB = (const v2f*)(W_ih2 + rowB * HH);
        const v2f* qA = (const v2f*)(W_hh2 + rowA * HH);
        const v2f* qB = (const v2f*)(W_hh2 + rowB * HH);
#pragma unroll
        for (int r = 0; r < 16; ++r) { m1A[r] = pA[r]; m1B[r] = pB[r];
                                       m2A[r] = qA[r]; m2B[r] = qB[r]; }
        bA  = b_ih2[rowA] + b_hh2[rowA];
        bB  = b_ih2[rowB] + b_hh2[rowB];
    }
    blin = b_lin[0];

    float cA = 0.f, cB = 0.f;        // c1 (wave0) / c2 (wave1)
    // carried dots: w0: Whh1·h1(t-1); w1: Whh2·h2(t-1)
    v2f p0 = {0.f,0.f}, p1 = {0.f,0.f}, p2 = {0.f,0.f}, p3 = {0.f,0.f};

    const float* __restrict__ inp  = input + (size_t)b * T;
    float* __restrict__       outp = out   + (size_t)b * total;

    // ================= Teacher-forced phase: chunk pipeline, rebalanced ==========
    if (w == 0) {
        int t = 0;
        float xcur = inp[0];
        for (int cb = 0; t < T; ++cb) {
            float* zbuf = zring + (cb & 1) * (KCH * 128);
            int S = T - t; if (S > KCH) S = KCH;
            for (int s = 0; s < S; ++s, ++t) {
                float x = xcur;
                int tn = t + 1;
                xcur = inp[tn < T ? tn : 0];            // prefetch, off-path
                v2f tA = p0 + p1, tB = p2 + p3;
                float z1A = fmaf(x, wxA, bA + tA.x + tA.y);
                float z1B = fmaf(x, wxB, bB + tB.x + tB.y);
                float hA, hB;
                gate_hc(z1A, z1B, es, mm, cc, cA, cB, hA, hB);
                if (q == 0) { h1self[ch] = hA; h1self[ch + 16] = hB; }
                v2f hv[16]; load_bc(h1self, hv);         // same-wave round trip
                dot2<false>(hv, m1A, m1B, p0, p1, p2, p3);   // Whh1·h1(t) carry
                v2f s0, s1, s2, s3;
                dot2<false>(hv, m2A, m2B, s0, s1, s2, s3);   // Wih2·h1(t) for w1
                v2f uA = s0 + s1, uB = s2 + s3;
                float* zs = zbuf + s * 128;
                zs[zidx]      = uA.x + uA.y;             // 2 lanes/bank: conflict-free
                zs[zidx + 64] = uB.x + uB.y;
            }
            __syncthreads();          // chunk (zring half) published
        }
        __syncthreads();              // match consumer
    } else {
        __syncthreads();              // wait for chunk 0
        int t = 0;
        for (int cb = 0; t < T; ++cb) {
            const float* zbuf = zring + (cb & 1) * (KCH * 128);
            int S = T - t; if (S > KCH) S = KCH;
            for (int s = 0; s < S; ++s, ++t) {
                const float* zs = zbuf + s * 128;
                float zihA = zs[zidx], zihB = zs[zidx + 64];
                v2f tA = p0 + p1, tB = p2 + p3;
                float z2A = bA + zihA + tA.x + tA.y;     // bias + Wih2·h1 + Whh2·h2
                float z2B = bB + zihB + tB.x + tB.y;
                float hA, hB;
                gate_hc(z2A, z2B, es, mm, cc, cA, cB, hA, hB);
                if (q == 0) { h2s[ch] = hA; h2s[ch + 16] = hB; }
                v2f gv[16]; load_bc(h2s, gv);            // same-wave round trip
                dot2<false>(gv, m2A, m2B, p0, p1, p2, p3);   // Whh2·h2(t) carry
                float pr = fmaf(hA, wlA, hB * wlB);
                float ov = out_reduce(pr) + blin;
                if (lane == 0) outp[t] = ov;
            }
            __syncthreads();
        }
    }

    // ================= Autoregressive phase: r2-verified 2-wave, 2 barriers/step ==
    // w0 recomputes x(t) = Wlin·h2(t-1)+b per-lane from the h2s broadcast.
    v2f wl[16];
    if (w == 0) {                     // m2 (Wih2 copy) dead after TF -> RA reuses
        const v2f* wp = (const v2f*)W_lin;
#pragma unroll
        for (int r = 0; r < 16; ++r) wl[r] = wp[r];
    }
    for (int t = T; t < total; ++t) {
        __syncthreads();                        // BX: h2s(t-1) visible, h1x WAR safe
        if (w == 0) {
            v2f gv[16]; load_bc(h2s, gv);
            v2f oa = gv[0] * wl[0], ob = gv[1] * wl[1];
#pragma unroll
            for (int r = 2; r < 16; r += 2) { oa = pk_fma(gv[r],   wl[r],   oa);
                                              ob = pk_fma(gv[r+1], wl[r+1], ob); }
            float xo = (oa.x + oa.y) + (ob.x + ob.y) + blin;   // = out(t-1)
            if (t > T && lane == 0) outp[t - 1] = xo;          // outp[T-1] done by TF
            v2f tA = p0 + p1, tB = p2 + p3;
            float z1A = fmaf(xo, wxA, bA + tA.x + tA.y);
            float z1B = fmaf(xo, wxB, bB + tB.x + tB.y);
            float hA, hB;
            gate_hc(z1A, z1B, es, mm, cc, cA, cB, hA, hB);
            if (q == 0) { h1x[ch] = hA; h1x[ch + 16] = hB; }
        } else {
            v2f gv[16]; load_bc(h2s, gv);       // own write from prev step
            dot2<false>(gv, m2A, m2B, p0, p1, p2, p3);   // refresh Whh2·h2 carry
        }
        __syncthreads();                        // BH: h1x visible
        if (w == 0) {
            v2f hv[16]; load_bc(h1x, hv);       // next z1 carry (shadow)
            dot2<false>(hv, m1A, m1B, p0, p1, p2, p3);
        } else {
            v2f hv[16]; load_bc(h1x, hv);
            dot2<true>(hv, m1A, m1B, p0, p1, p2, p3);    // in place: p dead after z2
            v2f tA = p0 + p1, tB = p2 + p3;
            float z2A = bA + tA.x + tA.y;
            float z2B = bB + tB.x + tB.y;
            float hA, hB;
            gate_hc(z2A, z2B, es, mm, cc, cA, cB, hA, hB);
            if (q == 0) { h2s[ch] = hA; h2s[ch + 16] = hB; }
        }
    }
    // tail: final output out(total-1) = Wlin·h2(total-1)+b
    __syncthreads();
    if (w == 0) {
        v2f gv[16]; load_bc(h2s, gv);
        v2f oa = gv[0] * wl[0], ob = gv[1] * wl[1];
#pragma unroll
        for (int r = 2; r < 16; r += 2) { oa = pk_fma(gv[r],   wl[r],   oa);
                                          ob = pk_fma(gv[r+1], wl[r+1], ob); }
        if (lane == 0) outp[total - 1] = (oa.x + oa.y) + (ob.x + ob.y) + blin;
    }
}

extern "C" void kernel_launch(void* const* d_in, const int* in_sizes, int n_in,
                              void* d_out, int out_size, void* d_ws, size_t ws_size,
                              hipStream_t stream) {
    const int B = 1024;                 // fixed by the source module
    const int T = in_sizes[0] / B;      // 999
    const int total = out_size / B;     // T + future = 1999

    lstm_seq_kernel<<<dim3(B), dim3(128), 0, stream>>>(
        (const float*)d_in[0],
        (const float*)d_in[1], (const float*)d_in[2],
        (const float*)d_in[3], (const float*)d_in[4],
        (const float*)d_in[5], (const float*)d_in[6],
        (const float*)d_in[7], (const float*)d_in[8],
        (const float*)d_in[9], (const float*)d_in[10],
        (float*)d_out, T, total);
}